// Round 13
// baseline (287.469 us; speedup 1.0000x reference)
//
#include <hip/hip_runtime.h>
#include <hip/hip_bf16.h>

#define IN_DIM 128
#define CAP 64   // bucket capacity per (dst,etype) segment; Poisson(8) => P(deg>=64) ~ 1e-40

typedef __hip_bfloat16 bf16;
typedef __attribute__((ext_vector_type(8))) short frag8;   // 8 bf16 (4 VGPRs)
typedef __attribute__((ext_vector_type(4))) float f32x4;   // MFMA C/D
typedef __attribute__((ext_vector_type(2))) float f32x2;   // dual-issue v_pk_*_f32

// ---------------- tiny zero-fill ----------------
__global__ void k_zero(int4* __restrict__ p, int n4) {
  int i = blockIdx.x * 256 + threadIdx.x;
  if (i < n4) p[i] = int4{0, 0, 0, 0};
}

// ---------------- bucket-CSR build: one atomic pass + direct scatter ----------------

__global__ void k_rank(const int* __restrict__ dst, const int* __restrict__ et,
                       int* __restrict__ deg, int* __restrict__ rank, int E) {
  int i = blockIdx.x * 256 + threadIdx.x;
  if (i < E) rank[i] = atomicAdd(&deg[2 * dst[i] + et[i]], 1);
}

__global__ void k_scatter(const int* __restrict__ src, const int* __restrict__ dst,
                          const int* __restrict__ et, const int* __restrict__ rank,
                          int* __restrict__ packed, int E) {
  int i = blockIdx.x * 512 + threadIdx.x;
  int i2 = i + 256;
  if (i < E) {
    int k0 = 2 * dst[i] + et[i];
    int r0 = rank[i], s0 = src[i];
    if (i2 < E) {
      int k1 = 2 * dst[i2] + et[i2];
      int r1 = rank[i2], s1 = src[i2];
      packed[k0 * CAP + r0] = s0;
      packed[k1 * CAP + r1] = s1;
    } else {
      packed[k0 * CAP + r0] = s0;
    }
  }
}

// ---------------- weight prep (merged) ----------------
// All B-matrices stored transposed [NCOL][K] bf16, pre-XOR-swizzled:
// storage (c, ks) holds logical k = ks ^ ((c&7)<<3)  (involution within 64-elem blocks)
// UW [3][64][320]: k 0..63 = W2[0]@nW1_msg0, 64..127 = W2[1]@nW1_msg1,
// 128/129 = b2@nW1 indicator rows, 130..191 zero, 192..319 = nW1 h-part.

__global__ void k_prep(const float* __restrict__ eW1, const float* __restrict__ eb1,
                       const float* __restrict__ eW2, const float* __restrict__ eb2,
                       const float* __restrict__ nW1, const float* __restrict__ nW2,
                       bf16* __restrict__ WcatT, float* __restrict__ bcat,
                       bf16* __restrict__ nW2T, bf16* __restrict__ UW) {
  int idx = blockIdx.x * 256 + threadIdx.x;
  if (idx < 3 * 256 * 128) {        // WcatT
    int l = idx / (256 * 128);
    int rr = idx % (256 * 128);
    int c = rr >> 7, ks = rr & 127;
    int k = ks ^ ((c & 7) << 3);
    int e = (c >> 6) & 1;
    int row = (c < 128) ? k : 128 + k;
    WcatT[idx] = __float2bfloat16(eW1[((l * 2 + e) * 256 + row) * 64 + (c & 63)]);
  }
  int i2 = idx - 3 * 256 * 128;
  if (i2 >= 0 && i2 < 3 * 128 * 64) {   // nW2T
    int l = i2 / (128 * 64);
    int rr = i2 % (128 * 64);
    int c = rr >> 6, ks = rr & 63;
    int k = ks ^ ((c & 7) << 3);
    nW2T[i2] = __float2bfloat16(nW2[(l * 64 + k) * 128 + c]);
  }
  int i3 = i2 - 3 * 128 * 64;
  if (i3 >= 0 && i3 < 3 * 64 * 320) {   // UW
    int l = i3 / (64 * 320);
    int rr = i3 % (64 * 320);
    int c = rr / 320, ks = rr % 320;
    int k = ks ^ ((c & 7) << 3);
    float v = 0.f;
    if (k < 64) {
      for (int m = 0; m < 32; ++m)
        v += eW2[((l * 2 + 0) * 64 + k) * 32 + m] * nW1[(l * 192 + m) * 64 + c];
    } else if (k < 128) {
      for (int m = 0; m < 32; ++m)
        v += eW2[((l * 2 + 1) * 64 + (k - 64)) * 32 + m] * nW1[(l * 192 + 32 + m) * 64 + c];
    } else if (k == 128) {
      for (int m = 0; m < 32; ++m)
        v += eb2[(l * 2 + 0) * 32 + m] * nW1[(l * 192 + m) * 64 + c];
    } else if (k == 129) {
      for (int m = 0; m < 32; ++m)
        v += eb2[(l * 2 + 1) * 32 + m] * nW1[(l * 192 + 32 + m) * 64 + c];
    } else if (k >= 192) {
      v = nW1[(l * 192 + 64 + (k - 192)) * 64 + c];
    }
    UW[i3] = __float2bfloat16(v);
  }
  if (idx < 3 * 256) {                  // bcat (b1 folded into B-columns)
    int l = idx >> 8, c = idx & 255;
    float b = 0.f;
    if (c >= 128) {
      int e = (c >> 6) & 1;
      b = eb1[(l * 2 + e) * 64 + (c & 63)];
    }
    bcat[idx] = b;
  }
}

__global__ void k_cast(const float* __restrict__ in, bf16* __restrict__ out, int n4) {
  int i = blockIdx.x * 256 + threadIdx.x;
  if (i < n4) {
    float4 v = *reinterpret_cast<const float4*>(in + (size_t)i * 4);
    bf16* o = out + (size_t)i * 4;
    o[0] = __float2bfloat16(v.x);
    o[1] = __float2bfloat16(v.y);
    o[2] = __float2bfloat16(v.z);
    o[3] = __float2bfloat16(v.w);
  }
}

// ---------------- P-build GEMM: [PA|PB] = h @ Wcat + bcat (bf16) ----------------

__global__ __launch_bounds__(256) void k_pgemm(
    const bf16* __restrict__ h, const bf16* __restrict__ Wt,
    const float* __restrict__ bias, bf16* __restrict__ PA, bf16* __restrict__ PB, int M) {
  __shared__ char lds_a[64 * 256];    // swizzled A panel
  __shared__ char lds_b[128 * 256];   // pre-swizzled B panel
  int t = threadIdx.x;
  int m0 = blockIdx.x * 64;
  int cb = blockIdx.y * 128;
  bf16* out = blockIdx.y ? PB : PA;
  {
    const char* hc = (const char*)h;
#pragma unroll
    for (int it = 0; it < 4; ++it) {
      int c = t + it * 256;
      int row = c >> 4, k16 = (c & 15) << 4;
      int gr = m0 + row; if (gr >= M) gr = M - 1;
      uint4 v = *reinterpret_cast<const uint4*>(hc + (size_t)gr * 256 + k16);
      *reinterpret_cast<uint4*>(lds_a + row * 256 + (k16 ^ ((row & 7) << 4))) = v;
    }
    const uint4* g = reinterpret_cast<const uint4*>((const char*)Wt + (size_t)cb * 256);
    uint4* l = reinterpret_cast<uint4*>(lds_b);
#pragma unroll
    for (int it = 0; it < 8; ++it) l[t + it * 256] = g[t + it * 256];
  }
  __syncthreads();
  int lane = t & 63, w = t >> 6;
  int wm = w >> 1, wn = w & 1;
  int r = lane & 15, q = lane >> 4;
  f32x4 acc[2][4] = {};
#pragma unroll
  for (int kc = 0; kc < 128; kc += 32) {
    int kk2 = (kc + q * 8) * 2;
    frag8 a[2];
#pragma unroll
    for (int fm = 0; fm < 2; ++fm) {
      int row = wm * 32 + fm * 16 + r;
      a[fm] = *reinterpret_cast<const frag8*>(lds_a + row * 256 + (kk2 ^ ((row & 7) << 4)));
    }
#pragma unroll
    for (int fn = 0; fn < 4; ++fn) {
      int c = wn * 64 + fn * 16 + r;
      frag8 b = *reinterpret_cast<const frag8*>(lds_b + c * 256 + (kk2 ^ ((c & 7) << 4)));
      acc[0][fn] = __builtin_amdgcn_mfma_f32_16x16x32_bf16(a[0], b, acc[0][fn], 0, 0, 0);
      acc[1][fn] = __builtin_amdgcn_mfma_f32_16x16x32_bf16(a[1], b, acc[1][fn], 0, 0, 0);
    }
  }
#pragma unroll
  for (int fm = 0; fm < 2; ++fm) {
    int grow_base = m0 + wm * 32 + fm * 16 + q * 4;
#pragma unroll
    for (int fn = 0; fn < 4; ++fn) {
      int lcol = wn * 64 + fn * 16 + r;
      float bv = bias[cb + lcol];
#pragma unroll
      for (int i = 0; i < 4; ++i) {
        int grow = grow_base + i;
        if (grow >= M) continue;
        out[(size_t)grow * 128 + lcol] = __float2bfloat16(acc[fm][fn][i] + bv);
      }
    }
  }
}

// ---------------- fused node MLP: h' = (relu([macc|h]@UW + nb1)) @ nW2 + nb2 ----------------

template <bool OUT_BF16>
__global__ __launch_bounds__(256) void k_node(
    const bf16* __restrict__ macc, const bf16* __restrict__ h,
    const bf16* __restrict__ UWl, const float* __restrict__ nb1l,
    const bf16* __restrict__ W2l, const float* __restrict__ nb2l,
    void* __restrict__ out, int M) {
  __shared__ char lds_uw[64 * 320 * 2];   // 40960 B; first 8192 B reused as U-tile
  __shared__ char lds_w2[128 * 64 * 2];   // 16384 B
  char* lds_u = lds_uw;
  int t = threadIdx.x;
  int m0 = blockIdx.x * 64;
  {
    const uint4* g1 = reinterpret_cast<const uint4*>(UWl);
    uint4* l1 = reinterpret_cast<uint4*>(lds_uw);
    for (int i = t; i < 2560; i += 256) l1[i] = g1[i];
    const uint4* g2 = reinterpret_cast<const uint4*>(W2l);
    uint4* l2 = reinterpret_cast<uint4*>(lds_w2);
    for (int i = t; i < 1024; i += 256) l2[i] = g2[i];
  }
  __syncthreads();
  int lane = t & 63, w = t >> 6;
  int r = lane & 15, q = lane >> 4;
  int wm = w >> 1, wn = w & 1;
  f32x4 acc[2][2] = {};
  {
    int row0 = m0 + wm * 32 + r;
    int row1 = row0 + 16;
    if (row0 >= M) row0 = M - 1;
    if (row1 >= M) row1 = M - 1;
#pragma unroll
    for (int kc = 0; kc < 320; kc += 32) {
      int kk = kc + q * 8;
      frag8 a0, a1;
      if (kc >= 192) {
        a0 = *reinterpret_cast<const frag8*>(h + (size_t)row0 * 128 + (kk - 192));
        a1 = *reinterpret_cast<const frag8*>(h + (size_t)row1 * 128 + (kk - 192));
      } else {
        a0 = *reinterpret_cast<const frag8*>(macc + (size_t)row0 * 192 + kk);
        a1 = *reinterpret_cast<const frag8*>(macc + (size_t)row1 * 192 + kk);
      }
#pragma unroll
      for (int fn = 0; fn < 2; ++fn) {
        int c = wn * 32 + fn * 16 + r;
        int byte = c * 640 + ((kk * 2) ^ ((c & 7) << 4));
        frag8 b = *reinterpret_cast<const frag8*>(lds_uw + byte);
        acc[0][fn] = __builtin_amdgcn_mfma_f32_16x16x32_bf16(a0, b, acc[0][fn], 0, 0, 0);
        acc[1][fn] = __builtin_amdgcn_mfma_f32_16x16x32_bf16(a1, b, acc[1][fn], 0, 0, 0);
      }
    }
  }
  __syncthreads();
#pragma unroll
  for (int fm = 0; fm < 2; ++fm) {
    int lrow_base = wm * 32 + fm * 16 + q * 4;
#pragma unroll
    for (int fn = 0; fn < 2; ++fn) {
      int col = wn * 32 + fn * 16 + r;
      float bv = nb1l[col];
#pragma unroll
      for (int i = 0; i < 4; ++i) {
        int lrow = lrow_base + i;
        float v = fmaxf(acc[fm][fn][i] + bv, 0.f);
        int byte = lrow * 128 + ((col * 2) ^ ((lrow & 7) << 4));
        *reinterpret_cast<bf16*>(lds_u + byte) = __float2bfloat16(v);
      }
    }
  }
  __syncthreads();
  f32x4 acc2[2][4] = {};
#pragma unroll
  for (int kc = 0; kc < 64; kc += 32) {
    int kk = kc + q * 8;
    frag8 a[2];
#pragma unroll
    for (int fm = 0; fm < 2; ++fm) {
      int rg = wm * 32 + fm * 16 + r;
      int abyte = rg * 128 + ((kk * 2) ^ ((rg & 7) << 4));
      a[fm] = *reinterpret_cast<const frag8*>(lds_u + abyte);
    }
#pragma unroll
    for (int fn = 0; fn < 4; ++fn) {
      int c = wn * 64 + fn * 16 + r;
      int bbyte = c * 128 + ((kk * 2) ^ ((c & 7) << 4));
      frag8 b = *reinterpret_cast<const frag8*>(lds_w2 + bbyte);
      acc2[0][fn] = __builtin_amdgcn_mfma_f32_16x16x32_bf16(a[0], b, acc2[0][fn], 0, 0, 0);
      acc2[1][fn] = __builtin_amdgcn_mfma_f32_16x16x32_bf16(a[1], b, acc2[1][fn], 0, 0, 0);
    }
  }
#pragma unroll
  for (int fm = 0; fm < 2; ++fm) {
    int grow_base = m0 + wm * 32 + fm * 16 + q * 4;
#pragma unroll
    for (int fn = 0; fn < 4; ++fn) {
      int gcol = wn * 64 + fn * 16 + r;
      float bv = nb2l[gcol];
#pragma unroll
      for (int i = 0; i < 4; ++i) {
        int grow = grow_base + i;
        if (grow >= M) continue;
        float v = acc2[fm][fn][i] + bv;
        if (OUT_BF16) ((bf16*)out)[(size_t)grow * 128 + gcol] = __float2bfloat16(v);
        else          ((float*)out)[(size_t)grow * 128 + gcol] = v;
      }
    }
  }
}

// ---------------- edge phase (16-slot wide gather-mean, 4 gathers in flight) ----------------
// PA per node: [A0(64) | A1(64)] bf16; PB: [B0+b1 | B1+b1].
// macc per node: [mean_e0(64) | mean_e1(64) | ind0,ind1 | 0-pad to 192] bf16.
// One wave per node; halves = etypes; per half 4 groups x 8 lanes; each trip covers
// 16 edge slots (groups at +0,+4,+8,+12) -> 4 independent 128-B gathers in flight.
// Poisson(8) degrees => ~98% of segments finish in ONE trip (no serial trip chain).

__device__ __forceinline__ unsigned pack_bf2(float lo, float hi) {
  __hip_bfloat162 h2{__float2bfloat16(lo), __float2bfloat16(hi)};
  return *reinterpret_cast<unsigned*>(&h2);
}
__device__ __forceinline__ f32x2 unpk(unsigned v) {
  return f32x2{__uint_as_float(v << 16), __uint_as_float(v & 0xffff0000u)};
}
template <int IMM>
__device__ __forceinline__ f32x2 swz2(f32x2 x) {
  f32x2 r;
  r.x = __int_as_float(__builtin_amdgcn_ds_swizzle(__float_as_int(x.x), IMM));
  r.y = __int_as_float(__builtin_amdgcn_ds_swizzle(__float_as_int(x.y), IMM));
  return r;
}

__global__ __launch_bounds__(256) void k_edge(const bf16* __restrict__ PA,
                                              const bf16* __restrict__ PB,
                                              const int* __restrict__ deg,
                                              const int* __restrict__ packed,
                                              bf16* __restrict__ macc, int n) {
  int wid = (blockIdx.x * 256 + threadIdx.x) >> 6;
  int nw = (gridDim.x * 256) >> 6;
  int lane = threadIdx.x & 63;
  int half = lane >> 5;
  int hl = lane & 31;
  int g = hl >> 3;
  int j = hl & 7;
  const char* PAc = (const char*)PA;
  const char* PBc = (const char*)PB;
  int laneoff = half * 128 + j * 16;   // byte offset inside a 256-B PA/PB row
  for (int node = wid; node < n; node += nw) {
    int2 d01 = *reinterpret_cast<const int2*>(deg + 2 * node);
    int len0 = d01.x, len1 = d01.y;
    int base = (2 * node + half) * CAP;
    int lim = base + (half ? len1 : len0);
    uint4 bu = *reinterpret_cast<const uint4*>(PBc + (size_t)node * 256 + laneoff);
    f32x2 b0 = unpk(bu.x), b1 = unpk(bu.y), b2 = unpk(bu.z), b3 = unpk(bu.w);
    int maxlen = max(len0, len1);
    int trips = (maxlen + 15) >> 4;
    f32x2 acc0{0.f, 0.f}, acc1{0.f, 0.f}, acc2{0.f, 0.f}, acc3{0.f, 0.f};
    for (int i = 0; i < trips; ++i) {
      int e0 = base + 16 * i + g;
      int e1 = e0 + 4, e2 = e0 + 8, e3 = e0 + 12;
      int s0 = 0, s1 = 0, s2 = 0, s3 = 0;
      if (e0 < lim) s0 = packed[e0];
      if (e1 < lim) s1 = packed[e1];
      if (e2 < lim) s2 = packed[e2];
      if (e3 < lim) s3 = packed[e3];
      uint4 v0 = *reinterpret_cast<const uint4*>(PAc + (size_t)s0 * 256 + laneoff);
      uint4 v1 = *reinterpret_cast<const uint4*>(PAc + (size_t)s1 * 256 + laneoff);
      uint4 v2 = *reinterpret_cast<const uint4*>(PAc + (size_t)s2 * 256 + laneoff);
      uint4 v3 = *reinterpret_cast<const uint4*>(PAc + (size_t)s3 * 256 + laneoff);
      float ok0 = (e0 < lim) ? 1.f : 0.f;
      float ok1 = (e1 < lim) ? 1.f : 0.f;
      float ok2 = (e2 < lim) ? 1.f : 0.f;
      float ok3 = (e3 < lim) ? 1.f : 0.f;
      f32x2 z{0.f, 0.f};
      f32x2 k0{ok0, ok0}, k1{ok1, ok1}, k2{ok2, ok2}, k3{ok3, ok3};
      acc0 = __builtin_elementwise_max(unpk(v0.x) + b0, z) * k0 + acc0;
      acc1 = __builtin_elementwise_max(unpk(v0.y) + b1, z) * k0 + acc1;
      acc2 = __builtin_elementwise_max(unpk(v0.z) + b2, z) * k0 + acc2;
      acc3 = __builtin_elementwise_max(unpk(v0.w) + b3, z) * k0 + acc3;
      acc0 = __builtin_elementwise_max(unpk(v1.x) + b0, z) * k1 + acc0;
      acc1 = __builtin_elementwise_max(unpk(v1.y) + b1, z) * k1 + acc1;
      acc2 = __builtin_elementwise_max(unpk(v1.z) + b2, z) * k1 + acc2;
      acc3 = __builtin_elementwise_max(unpk(v1.w) + b3, z) * k1 + acc3;
      acc0 = __builtin_elementwise_max(unpk(v2.x) + b0, z) * k2 + acc0;
      acc1 = __builtin_elementwise_max(unpk(v2.y) + b1, z) * k2 + acc1;
      acc2 = __builtin_elementwise_max(unpk(v2.z) + b2, z) * k2 + acc2;
      acc3 = __builtin_elementwise_max(unpk(v2.w) + b3, z) * k2 + acc3;
      acc0 = __builtin_elementwise_max(unpk(v3.x) + b0, z) * k3 + acc0;
      acc1 = __builtin_elementwise_max(unpk(v3.y) + b1, z) * k3 + acc1;
      acc2 = __builtin_elementwise_max(unpk(v3.z) + b2, z) * k3 + acc2;
      acc3 = __builtin_elementwise_max(unpk(v3.w) + b3, z) * k3 + acc3;
    }
    // butterfly over the 4 edge-slot groups of each half (xor 8, then 16)
    acc0 += swz2<0x201F>(acc0); acc1 += swz2<0x201F>(acc1);
    acc2 += swz2<0x201F>(acc2); acc3 += swz2<0x201F>(acc3);
    acc0 += swz2<0x401F>(acc0); acc1 += swz2<0x401F>(acc1);
    acc2 += swz2<0x401F>(acc2); acc3 += swz2<0x401F>(acc3);
    int len = half ? len1 : len0;
    float sc = (len > 0) ? 1.f / (float)len : 0.f;
    f32x2 sc2{sc, sc};
    acc0 *= sc2; acc1 *= sc2; acc2 *= sc2; acc3 *= sc2;
    bf16* mrow = macc + (size_t)node * 192;
    if (hl < 8) {
      uint4 o;
      o.x = pack_bf2(acc0.x, acc0.y);
      o.y = pack_bf2(acc1.x, acc1.y);
      o.z = pack_bf2(acc2.x, acc2.y);
      o.w = pack_bf2(acc3.x, acc3.y);
      *reinterpret_cast<uint4*>(mrow + half * 64 + j * 8) = o;
    } else if (half == 0 && hl < 16) {
      // elems 128..191: lane 8 writes {ind0,ind1, 0...}, lanes 9..15 write zeros
      unsigned w0 = (hl == 8) ? pack_bf2(len0 > 0 ? 1.f : 0.f, len1 > 0 ? 1.f : 0.f) : 0u;
      uint4 o{w0, 0u, 0u, 0u};
      *reinterpret_cast<uint4*>(mrow + 128 + (hl - 8) * 8) = o;
    }
  }
}

// ---------------- launch ----------------

extern "C" void kernel_launch(void* const* d_in, const int* in_sizes, int n_in,
                              void* d_out, int out_size, void* d_ws, size_t ws_size,
                              hipStream_t stream) {
  const float* nf  = (const float*)d_in[0];
  const float* eW1 = (const float*)d_in[1];
  const float* eb1 = (const float*)d_in[2];
  const float* eW2 = (const float*)d_in[3];
  const float* eb2 = (const float*)d_in[4];
  const float* nW1 = (const float*)d_in[5];
  const float* nb1 = (const float*)d_in[6];
  const float* nW2 = (const float*)d_in[7];
  const float* nb2 = (const float*)d_in[8];
  const int* src = (const int*)d_in[9];
  const int* dst = (const int*)d_in[10];
  const int* et  = (const int*)d_in[11];
  const int N = in_sizes[0] / IN_DIM;
  const int E = in_sizes[9];
  const int M = 2 * N;

  char* wp = (char*)d_ws;
  auto alloc = [&](size_t bytes) {
    char* p = wp; wp += (bytes + 255) & ~(size_t)255; return p;
  };
  int*   deg       = (int*)alloc((size_t)M * 4);
  int*   rank      = (int*)alloc((size_t)E * 4);
  int*   packed    = (int*)alloc((size_t)M * CAP * 4);
  bf16*  WcatT     = (bf16*)alloc((size_t)3 * 256 * 128 * 2);
  float* bcat      = (float*)alloc((size_t)3 * 256 * 4);
  bf16*  UW        = (bf16*)alloc((size_t)3 * 64 * 320 * 2);
  bf16*  nW2T      = (bf16*)alloc((size_t)3 * 128 * 64 * 2);
  bf16*  PA        = (bf16*)alloc((size_t)N * 128 * 2);
  bf16*  PB        = (bf16*)alloc((size_t)N * 128 * 2);
  bf16*  macc      = (bf16*)alloc((size_t)N * 192 * 2);
  bf16*  hb0       = (bf16*)alloc((size_t)N * 128 * 2);
  bf16*  hb1       = (bf16*)alloc((size_t)N * 128 * 2);

  int n4 = (M + 3) / 4;    // deg zero-fill in int4 units
  k_zero<<<(n4 + 255) / 256, 256, 0, stream>>>((int4*)deg, n4);
  k_rank<<<(E + 255) / 256, 256, 0, stream>>>(dst, et, deg, rank, E);
  k_scatter<<<(E + 511) / 512, 256, 0, stream>>>(src, dst, et, rank, packed, E);
  int prep_work = 3 * 256 * 128 + 3 * 128 * 64 + 3 * 64 * 320;
  k_prep<<<(prep_work + 255) / 256, 256, 0, stream>>>(
      eW1, eb1, eW2, eb2, nW1, nW2, WcatT, bcat, nW2T, UW);
  k_cast<<<((N * 128 / 4) + 255) / 256, 256, 0, stream>>>(nf, hb0, N * 128 / 4);

  int gm = (N + 63) / 64;
  bf16* hbs[2] = {hb0, hb1};
  for (int l = 0; l < 3; ++l) {
    const bf16* h = hbs[l & 1];
    bf16* hn = hbs[(l + 1) & 1];
    // [PA|PB] = h @ Wcat[l] + bcat[l]
    k_pgemm<<<dim3(gm, 2), 256, 0, stream>>>(
        h, WcatT + (size_t)l * 256 * 128, bcat + l * 256, PA, PB, N);
    // gather-mean -> macc [N,192] (writes pad zeros too)
    k_edge<<<4096, 256, 0, stream>>>(PA, PB, deg, packed, macc, N);
    // fused node MLP: h' = relu([macc|h]@UW + nb1) @ nW2 + nb2
    if (l == 2) {
      k_node<false><<<gm, 256, 0, stream>>>(
          macc, h, UW + (size_t)l * 64 * 320, nb1 + l * 64,
          nW2T + (size_t)l * 128 * 64, nb2 + l * 128, d_out, N);
    } else {
      k_node<true><<<gm, 256, 0, stream>>>(
          macc, h, UW + (size_t)l * 64 * 320, nb1 + l * 64,
          nW2T + (size_t)l * 128 * 64, nb2 + l * 128, hn, N);
    }
  }
}

// Round 14
// 280.425 us; speedup vs baseline: 1.0251x; 1.0251x over previous
//
#include <hip/hip_runtime.h>
#include <hip/hip_bf16.h>

#define IN_DIM 128
#define CAP 64   // bucket capacity per (dst,etype) segment; Poisson(8) => P(deg>=64) ~ 1e-40

typedef __hip_bfloat16 bf16;
typedef __attribute__((ext_vector_type(8))) short frag8;   // 8 bf16 (4 VGPRs)
typedef __attribute__((ext_vector_type(4))) float f32x4;   // MFMA C/D

// ---------------- tiny zero-fill ----------------
__global__ void k_zero(int4* __restrict__ p, int n4) {
  int i = blockIdx.x * 256 + threadIdx.x;
  if (i < n4) p[i] = int4{0, 0, 0, 0};
}

// ---------------- bucket-CSR build: one atomic pass + direct scatter ----------------

__global__ void k_rank(const int* __restrict__ dst, const int* __restrict__ et,
                       int* __restrict__ deg, int* __restrict__ rank, int E) {
  int i = blockIdx.x * 256 + threadIdx.x;
  if (i < E) rank[i] = atomicAdd(&deg[2 * dst[i] + et[i]], 1);
}

__global__ void k_scatter(const int* __restrict__ src, const int* __restrict__ dst,
                          const int* __restrict__ et, const int* __restrict__ rank,
                          int* __restrict__ packed, int E) {
  int i = blockIdx.x * 512 + threadIdx.x;
  int i2 = i + 256;
  if (i < E) {
    int k0 = 2 * dst[i] + et[i];
    int r0 = rank[i], s0 = src[i];
    if (i2 < E) {
      int k1 = 2 * dst[i2] + et[i2];
      int r1 = rank[i2], s1 = src[i2];
      packed[k0 * CAP + r0] = s0;
      packed[k1 * CAP + r1] = s1;
    } else {
      packed[k0 * CAP + r0] = s0;
    }
  }
}

// ---------------- weight prep (merged) ----------------
// All B-matrices stored transposed [NCOL][K] bf16, pre-XOR-swizzled:
// storage (c, ks) holds logical k = ks ^ ((c&7)<<3)  (involution within 64-elem blocks)
// UW [3][64][320]: k 0..63 = W2[0]@nW1_msg0, 64..127 = W2[1]@nW1_msg1,
// 128/129 = b2@nW1 indicator rows, 130..191 zero, 192..319 = nW1 h-part.

__global__ void k_prep(const float* __restrict__ eW1, const float* __restrict__ eb1,
                       const float* __restrict__ eW2, const float* __restrict__ eb2,
                       const float* __restrict__ nW1, const float* __restrict__ nW2,
                       bf16* __restrict__ WcatT, float* __restrict__ bcat,
                       bf16* __restrict__ nW2T, bf16* __restrict__ UW) {
  int idx = blockIdx.x * 256 + threadIdx.x;
  if (idx < 3 * 256 * 128) {        // WcatT
    int l = idx / (256 * 128);
    int rr = idx % (256 * 128);
    int c = rr >> 7, ks = rr & 127;
    int k = ks ^ ((c & 7) << 3);
    int e = (c >> 6) & 1;
    int row = (c < 128) ? k : 128 + k;
    WcatT[idx] = __float2bfloat16(eW1[((l * 2 + e) * 256 + row) * 64 + (c & 63)]);
  }
  int i2 = idx - 3 * 256 * 128;
  if (i2 >= 0 && i2 < 3 * 128 * 64) {   // nW2T
    int l = i2 / (128 * 64);
    int rr = i2 % (128 * 64);
    int c = rr >> 6, ks = rr & 63;
    int k = ks ^ ((c & 7) << 3);
    nW2T[i2] = __float2bfloat16(nW2[(l * 64 + k) * 128 + c]);
  }
  int i3 = i2 - 3 * 128 * 64;
  if (i3 >= 0 && i3 < 3 * 64 * 320) {   // UW
    int l = i3 / (64 * 320);
    int rr = i3 % (64 * 320);
    int c = rr / 320, ks = rr % 320;
    int k = ks ^ ((c & 7) << 3);
    float v = 0.f;
    if (k < 64) {
      for (int m = 0; m < 32; ++m)
        v += eW2[((l * 2 + 0) * 64 + k) * 32 + m] * nW1[(l * 192 + m) * 64 + c];
    } else if (k < 128) {
      for (int m = 0; m < 32; ++m)
        v += eW2[((l * 2 + 1) * 64 + (k - 64)) * 32 + m] * nW1[(l * 192 + 32 + m) * 64 + c];
    } else if (k == 128) {
      for (int m = 0; m < 32; ++m)
        v += eb2[(l * 2 + 0) * 32 + m] * nW1[(l * 192 + m) * 64 + c];
    } else if (k == 129) {
      for (int m = 0; m < 32; ++m)
        v += eb2[(l * 2 + 1) * 32 + m] * nW1[(l * 192 + 32 + m) * 64 + c];
    } else if (k >= 192) {
      v = nW1[(l * 192 + 64 + (k - 192)) * 64 + c];
    }
    UW[i3] = __float2bfloat16(v);
  }
  if (idx < 3 * 256) {                  // bcat (b1 folded into B-columns)
    int l = idx >> 8, c = idx & 255;
    float b = 0.f;
    if (c >= 128) {
      int e = (c >> 6) & 1;
      b = eb1[(l * 2 + e) * 64 + (c & 63)];
    }
    bcat[idx] = b;
  }
}

__global__ void k_cast(const float* __restrict__ in, bf16* __restrict__ out, int n4) {
  int i = blockIdx.x * 256 + threadIdx.x;
  if (i < n4) {
    float4 v = *reinterpret_cast<const float4*>(in + (size_t)i * 4);
    bf16* o = out + (size_t)i * 4;
    o[0] = __float2bfloat16(v.x);
    o[1] = __float2bfloat16(v.y);
    o[2] = __float2bfloat16(v.z);
    o[3] = __float2bfloat16(v.w);
  }
}

// ---------------- P-build GEMM: [PA|PB] = h @ Wcat + bcat (bf16) ----------------

__global__ __launch_bounds__(256) void k_pgemm(
    const bf16* __restrict__ h, const bf16* __restrict__ Wt,
    const float* __restrict__ bias, bf16* __restrict__ PA, bf16* __restrict__ PB, int M) {
  __shared__ char lds_a[64 * 256];    // swizzled A panel
  __shared__ char lds_b[128 * 256];   // pre-swizzled B panel
  int t = threadIdx.x;
  int m0 = blockIdx.x * 64;
  int cb = blockIdx.y * 128;
  bf16* out = blockIdx.y ? PB : PA;
  {
    const char* hc = (const char*)h;
#pragma unroll
    for (int it = 0; it < 4; ++it) {
      int c = t + it * 256;
      int row = c >> 4, k16 = (c & 15) << 4;
      int gr = m0 + row; if (gr >= M) gr = M - 1;
      uint4 v = *reinterpret_cast<const uint4*>(hc + (size_t)gr * 256 + k16);
      *reinterpret_cast<uint4*>(lds_a + row * 256 + (k16 ^ ((row & 7) << 4))) = v;
    }
    const uint4* g = reinterpret_cast<const uint4*>((const char*)Wt + (size_t)cb * 256);
    uint4* l = reinterpret_cast<uint4*>(lds_b);
#pragma unroll
    for (int it = 0; it < 8; ++it) l[t + it * 256] = g[t + it * 256];
  }
  __syncthreads();
  int lane = t & 63, w = t >> 6;
  int wm = w >> 1, wn = w & 1;
  int r = lane & 15, q = lane >> 4;
  f32x4 acc[2][4] = {};
#pragma unroll
  for (int kc = 0; kc < 128; kc += 32) {
    int kk2 = (kc + q * 8) * 2;
    frag8 a[2];
#pragma unroll
    for (int fm = 0; fm < 2; ++fm) {
      int row = wm * 32 + fm * 16 + r;
      a[fm] = *reinterpret_cast<const frag8*>(lds_a + row * 256 + (kk2 ^ ((row & 7) << 4)));
    }
#pragma unroll
    for (int fn = 0; fn < 4; ++fn) {
      int c = wn * 64 + fn * 16 + r;
      frag8 b = *reinterpret_cast<const frag8*>(lds_b + c * 256 + (kk2 ^ ((c & 7) << 4)));
      acc[0][fn] = __builtin_amdgcn_mfma_f32_16x16x32_bf16(a[0], b, acc[0][fn], 0, 0, 0);
      acc[1][fn] = __builtin_amdgcn_mfma_f32_16x16x32_bf16(a[1], b, acc[1][fn], 0, 0, 0);
    }
  }
#pragma unroll
  for (int fm = 0; fm < 2; ++fm) {
    int grow_base = m0 + wm * 32 + fm * 16 + q * 4;
#pragma unroll
    for (int fn = 0; fn < 4; ++fn) {
      int lcol = wn * 64 + fn * 16 + r;
      float bv = bias[cb + lcol];
#pragma unroll
      for (int i = 0; i < 4; ++i) {
        int grow = grow_base + i;
        if (grow >= M) continue;
        out[(size_t)grow * 128 + lcol] = __float2bfloat16(acc[fm][fn][i] + bv);
      }
    }
  }
}

// ---------------- fused node MLP: h' = (relu([macc|h]@UW + nb1)) @ nW2 + nb2 ----------------

template <bool OUT_BF16>
__global__ __launch_bounds__(256) void k_node(
    const bf16* __restrict__ macc, const bf16* __restrict__ h,
    const bf16* __restrict__ UWl, const float* __restrict__ nb1l,
    const bf16* __restrict__ W2l, const float* __restrict__ nb2l,
    void* __restrict__ out, int M) {
  __shared__ char lds_uw[64 * 320 * 2];   // 40960 B; first 8192 B reused as U-tile
  __shared__ char lds_w2[128 * 64 * 2];   // 16384 B
  char* lds_u = lds_uw;
  int t = threadIdx.x;
  int m0 = blockIdx.x * 64;
  {
    const uint4* g1 = reinterpret_cast<const uint4*>(UWl);
    uint4* l1 = reinterpret_cast<uint4*>(lds_uw);
    for (int i = t; i < 2560; i += 256) l1[i] = g1[i];
    const uint4* g2 = reinterpret_cast<const uint4*>(W2l);
    uint4* l2 = reinterpret_cast<uint4*>(lds_w2);
    for (int i = t; i < 1024; i += 256) l2[i] = g2[i];
  }
  __syncthreads();
  int lane = t & 63, w = t >> 6;
  int r = lane & 15, q = lane >> 4;
  int wm = w >> 1, wn = w & 1;
  f32x4 acc[2][2] = {};
  {
    int row0 = m0 + wm * 32 + r;
    int row1 = row0 + 16;
    if (row0 >= M) row0 = M - 1;
    if (row1 >= M) row1 = M - 1;
#pragma unroll
    for (int kc = 0; kc < 320; kc += 32) {
      int kk = kc + q * 8;
      frag8 a0, a1;
      if (kc >= 192) {
        a0 = *reinterpret_cast<const frag8*>(h + (size_t)row0 * 128 + (kk - 192));
        a1 = *reinterpret_cast<const frag8*>(h + (size_t)row1 * 128 + (kk - 192));
      } else {
        a0 = *reinterpret_cast<const frag8*>(macc + (size_t)row0 * 192 + kk);
        a1 = *reinterpret_cast<const frag8*>(macc + (size_t)row1 * 192 + kk);
      }
#pragma unroll
      for (int fn = 0; fn < 2; ++fn) {
        int c = wn * 32 + fn * 16 + r;
        int byte = c * 640 + ((kk * 2) ^ ((c & 7) << 4));
        frag8 b = *reinterpret_cast<const frag8*>(lds_uw + byte);
        acc[0][fn] = __builtin_amdgcn_mfma_f32_16x16x32_bf16(a0, b, acc[0][fn], 0, 0, 0);
        acc[1][fn] = __builtin_amdgcn_mfma_f32_16x16x32_bf16(a1, b, acc[1][fn], 0, 0, 0);
      }
    }
  }
  __syncthreads();
#pragma unroll
  for (int fm = 0; fm < 2; ++fm) {
    int lrow_base = wm * 32 + fm * 16 + q * 4;
#pragma unroll
    for (int fn = 0; fn < 2; ++fn) {
      int col = wn * 32 + fn * 16 + r;
      float bv = nb1l[col];
#pragma unroll
      for (int i = 0; i < 4; ++i) {
        int lrow = lrow_base + i;
        float v = fmaxf(acc[fm][fn][i] + bv, 0.f);
        int byte = lrow * 128 + ((col * 2) ^ ((lrow & 7) << 4));
        *reinterpret_cast<bf16*>(lds_u + byte) = __float2bfloat16(v);
      }
    }
  }
  __syncthreads();
  f32x4 acc2[2][4] = {};
#pragma unroll
  for (int kc = 0; kc < 64; kc += 32) {
    int kk = kc + q * 8;
    frag8 a[2];
#pragma unroll
    for (int fm = 0; fm < 2; ++fm) {
      int rg = wm * 32 + fm * 16 + r;
      int abyte = rg * 128 + ((kk * 2) ^ ((rg & 7) << 4));
      a[fm] = *reinterpret_cast<const frag8*>(lds_u + abyte);
    }
#pragma unroll
    for (int fn = 0; fn < 4; ++fn) {
      int c = wn * 64 + fn * 16 + r;
      int bbyte = c * 128 + ((kk * 2) ^ ((c & 7) << 4));
      frag8 b = *reinterpret_cast<const frag8*>(lds_w2 + bbyte);
      acc2[0][fn] = __builtin_amdgcn_mfma_f32_16x16x32_bf16(a[0], b, acc2[0][fn], 0, 0, 0);
      acc2[1][fn] = __builtin_amdgcn_mfma_f32_16x16x32_bf16(a[1], b, acc2[1][fn], 0, 0, 0);
    }
  }
#pragma unroll
  for (int fm = 0; fm < 2; ++fm) {
    int grow_base = m0 + wm * 32 + fm * 16 + q * 4;
#pragma unroll
    for (int fn = 0; fn < 4; ++fn) {
      int gcol = wn * 64 + fn * 16 + r;
      float bv = nb2l[gcol];
#pragma unroll
      for (int i = 0; i < 4; ++i) {
        int grow = grow_base + i;
        if (grow >= M) continue;
        float v = acc2[fm][fn][i] + bv;
        if (OUT_BF16) ((bf16*)out)[(size_t)grow * 128 + gcol] = __float2bfloat16(v);
        else          ((float*)out)[(size_t)grow * 128 + gcol] = v;
      }
    }
  }
}

// ---------------- edge phase (gather-mean over PA, bias from PB) ----------------
// PA per node: [A0(64) | A1(64)] bf16 (256 B rows) — random-gather working set 12.8 MB.
// PB per node: [B0+b1(64) | B1+b1(64)] bf16 — read once per node, coalesced.
// macc per node: [mean_e0(64) | mean_e1(64) | ind0,ind1 | 0-pad to 192] bf16.
// Segments live at packed[key*CAP .. key*CAP+deg[key]) (bucket layout, no scan).
// 8 edge slots/trip (2 gathers in flight), 2-deep index prefetch — best measured config.

__device__ __forceinline__ float u16lo(unsigned v) {
  return __uint_as_float(v << 16);
}
__device__ __forceinline__ float u16hi(unsigned v) {
  return __uint_as_float(v & 0xffff0000u);
}
__device__ __forceinline__ unsigned pack_bf2(float lo, float hi) {
  __hip_bfloat162 h2{__float2bfloat16(lo), __float2bfloat16(hi)};
  return *reinterpret_cast<unsigned*>(&h2);
}
template <int IMM>
__device__ __forceinline__ float swz_xor(float x) {
  return __int_as_float(__builtin_amdgcn_ds_swizzle(__float_as_int(x), IMM));
}

__global__ __launch_bounds__(256) void k_edge(const bf16* __restrict__ PA,
                                              const bf16* __restrict__ PB,
                                              const int* __restrict__ deg,
                                              const int* __restrict__ packed,
                                              bf16* __restrict__ macc, int n) {
  int wid = (blockIdx.x * 256 + threadIdx.x) >> 6;
  int nw = (gridDim.x * 256) >> 6;
  int lane = threadIdx.x & 63;
  int half = lane >> 5;
  int hl = lane & 31;
  int g = hl >> 3;
  int j = hl & 7;
  const char* PAc = (const char*)PA;
  const char* PBc = (const char*)PB;
  int laneoff = half * 128 + j * 16;   // byte offset inside a 256-B PA/PB row
  for (int node = wid; node < n; node += nw) {
    int2 d01 = *reinterpret_cast<const int2*>(deg + 2 * node);
    int len0 = d01.x, len1 = d01.y;
    int base = (2 * node + half) * CAP;
    int lim = base + (half ? len1 : len0);
    uint4 bu = *reinterpret_cast<const uint4*>(PBc + (size_t)node * 256 + laneoff);
    float b0 = u16lo(bu.x), b1 = u16hi(bu.x);
    float b2 = u16lo(bu.y), b3 = u16hi(bu.y);
    float b4 = u16lo(bu.z), b5 = u16hi(bu.z);
    float b6 = u16lo(bu.w), b7 = u16hi(bu.w);
    int trips = max((len0 + 7) >> 3, (len1 + 7) >> 3);
    float a0 = 0.f, a1 = 0.f, a2 = 0.f, a3 = 0.f;
    float a4 = 0.f, a5 = 0.f, a6 = 0.f, a7 = 0.f;
    int eA = base + g, eB = base + g + 4;
    int sA = 0, sB = 0;
    if (eA < lim) sA = packed[eA];
    if (eB < lim) sB = packed[eB];
    for (int i = 0; i < trips; ++i) {
      uint4 vA = *reinterpret_cast<const uint4*>(PAc + (size_t)sA * 256 + laneoff);
      uint4 vB = *reinterpret_cast<const uint4*>(PAc + (size_t)sB * 256 + laneoff);
      int eA2 = eA + 8, eB2 = eB + 8;
      int sA2 = 0, sB2 = 0;
      if (eA2 < lim) sA2 = packed[eA2];   // prefetch next trip's indices
      if (eB2 < lim) sB2 = packed[eB2];
      float okA = (eA < lim) ? 1.f : 0.f;
      float okB = (eB < lim) ? 1.f : 0.f;
      a0 = fmaf(fmaxf(u16lo(vA.x) + b0, 0.f), okA, a0);
      a1 = fmaf(fmaxf(u16hi(vA.x) + b1, 0.f), okA, a1);
      a2 = fmaf(fmaxf(u16lo(vA.y) + b2, 0.f), okA, a2);
      a3 = fmaf(fmaxf(u16hi(vA.y) + b3, 0.f), okA, a3);
      a4 = fmaf(fmaxf(u16lo(vA.z) + b4, 0.f), okA, a4);
      a5 = fmaf(fmaxf(u16hi(vA.z) + b5, 0.f), okA, a5);
      a6 = fmaf(fmaxf(u16lo(vA.w) + b6, 0.f), okA, a6);
      a7 = fmaf(fmaxf(u16hi(vA.w) + b7, 0.f), okA, a7);
      a0 = fmaf(fmaxf(u16lo(vB.x) + b0, 0.f), okB, a0);
      a1 = fmaf(fmaxf(u16hi(vB.x) + b1, 0.f), okB, a1);
      a2 = fmaf(fmaxf(u16lo(vB.y) + b2, 0.f), okB, a2);
      a3 = fmaf(fmaxf(u16hi(vB.y) + b3, 0.f), okB, a3);
      a4 = fmaf(fmaxf(u16lo(vB.z) + b4, 0.f), okB, a4);
      a5 = fmaf(fmaxf(u16hi(vB.z) + b5, 0.f), okB, a5);
      a6 = fmaf(fmaxf(u16lo(vB.w) + b6, 0.f), okB, a6);
      a7 = fmaf(fmaxf(u16hi(vB.w) + b7, 0.f), okB, a7);
      eA = eA2; eB = eB2; sA = sA2; sB = sB2;
    }
    a0 += swz_xor<0x201F>(a0); a1 += swz_xor<0x201F>(a1);
    a2 += swz_xor<0x201F>(a2); a3 += swz_xor<0x201F>(a3);
    a4 += swz_xor<0x201F>(a4); a5 += swz_xor<0x201F>(a5);
    a6 += swz_xor<0x201F>(a6); a7 += swz_xor<0x201F>(a7);
    a0 += swz_xor<0x401F>(a0); a1 += swz_xor<0x401F>(a1);
    a2 += swz_xor<0x401F>(a2); a3 += swz_xor<0x401F>(a3);
    a4 += swz_xor<0x401F>(a4); a5 += swz_xor<0x401F>(a5);
    a6 += swz_xor<0x401F>(a6); a7 += swz_xor<0x401F>(a7);
    int len = half ? len1 : len0;
    float sc = (len > 0) ? 1.f / (float)len : 0.f;
    bf16* mrow = macc + (size_t)node * 192;
    if (hl < 8) {
      uint4 o;
      o.x = pack_bf2(a0 * sc, a1 * sc);
      o.y = pack_bf2(a2 * sc, a3 * sc);
      o.z = pack_bf2(a4 * sc, a5 * sc);
      o.w = pack_bf2(a6 * sc, a7 * sc);
      *reinterpret_cast<uint4*>(mrow + half * 64 + j * 8) = o;
    } else if (half == 0 && hl < 16) {
      // elems 128..191: lane 8 writes {ind0,ind1, 0...}, lanes 9..15 write zeros
      unsigned w0 = (hl == 8) ? pack_bf2(len0 > 0 ? 1.f : 0.f, len1 > 0 ? 1.f : 0.f) : 0u;
      uint4 o{w0, 0u, 0u, 0u};
      *reinterpret_cast<uint4*>(mrow + 128 + (hl - 8) * 8) = o;
    }
  }
}

// ---------------- launch ----------------

extern "C" void kernel_launch(void* const* d_in, const int* in_sizes, int n_in,
                              void* d_out, int out_size, void* d_ws, size_t ws_size,
                              hipStream_t stream) {
  const float* nf  = (const float*)d_in[0];
  const float* eW1 = (const float*)d_in[1];
  const float* eb1 = (const float*)d_in[2];
  const float* eW2 = (const float*)d_in[3];
  const float* eb2 = (const float*)d_in[4];
  const float* nW1 = (const float*)d_in[5];
  const float* nb1 = (const float*)d_in[6];
  const float* nW2 = (const float*)d_in[7];
  const float* nb2 = (const float*)d_in[8];
  const int* src = (const int*)d_in[9];
  const int* dst = (const int*)d_in[10];
  const int* et  = (const int*)d_in[11];
  const int N = in_sizes[0] / IN_DIM;
  const int E = in_sizes[9];
  const int M = 2 * N;

  char* wp = (char*)d_ws;
  auto alloc = [&](size_t bytes) {
    char* p = wp; wp += (bytes + 255) & ~(size_t)255; return p;
  };
  int*   deg       = (int*)alloc((size_t)M * 4);
  int*   rank      = (int*)alloc((size_t)E * 4);
  int*   packed    = (int*)alloc((size_t)M * CAP * 4);
  bf16*  WcatT     = (bf16*)alloc((size_t)3 * 256 * 128 * 2);
  float* bcat      = (float*)alloc((size_t)3 * 256 * 4);
  bf16*  UW        = (bf16*)alloc((size_t)3 * 64 * 320 * 2);
  bf16*  nW2T      = (bf16*)alloc((size_t)3 * 128 * 64 * 2);
  bf16*  PA        = (bf16*)alloc((size_t)N * 128 * 2);
  bf16*  PB        = (bf16*)alloc((size_t)N * 128 * 2);
  bf16*  macc      = (bf16*)alloc((size_t)N * 192 * 2);
  bf16*  hb0       = (bf16*)alloc((size_t)N * 128 * 2);
  bf16*  hb1       = (bf16*)alloc((size_t)N * 128 * 2);

  int n4 = (M + 3) / 4;    // deg zero-fill in int4 units
  k_zero<<<(n4 + 255) / 256, 256, 0, stream>>>((int4*)deg, n4);
  k_rank<<<(E + 255) / 256, 256, 0, stream>>>(dst, et, deg, rank, E);
  k_scatter<<<(E + 511) / 512, 256, 0, stream>>>(src, dst, et, rank, packed, E);
  int prep_work = 3 * 256 * 128 + 3 * 128 * 64 + 3 * 64 * 320;
  k_prep<<<(prep_work + 255) / 256, 256, 0, stream>>>(
      eW1, eb1, eW2, eb2, nW1, nW2, WcatT, bcat, nW2T, UW);
  k_cast<<<((N * 128 / 4) + 255) / 256, 256, 0, stream>>>(nf, hb0, N * 128 / 4);

  int gm = (N + 63) / 64;
  bf16* hbs[2] = {hb0, hb1};
  for (int l = 0; l < 3; ++l) {
    const bf16* h = hbs[l & 1];
    bf16* hn = hbs[(l + 1) & 1];
    // [PA|PB] = h @ Wcat[l] + bcat[l]
    k_pgemm<<<dim3(gm, 2), 256, 0, stream>>>(
        h, WcatT + (size_t)l * 256 * 128, bcat + l * 256, PA, PB, N);
    // gather-mean -> macc [N,192] (writes pad zeros too)
    k_edge<<<4096, 256, 0, stream>>>(PA, PB, deg, packed, macc, N);
    // fused node MLP: h' = relu([macc|h]@UW + nb1) @ nW2 + nb2
    if (l == 2) {
      k_node<false><<<gm, 256, 0, stream>>>(
          macc, h, UW + (size_t)l * 64 * 320, nb1 + l * 64,
          nW2T + (size_t)l * 128 * 64, nb2 + l * 128, d_out, N);
    } else {
      k_node<true><<<gm, 256, 0, stream>>>(
          macc, h, UW + (size_t)l * 64 * 320, nb1 + l * 64,
          nW2T + (size_t)l * 128 * 64, nb2 + l * 128, hn, N);
    }
  }
}